// Round 6
// baseline (989.582 us; speedup 1.0000x reference)
//
#include <hip/hip_runtime.h>
#include <hip/hip_bf16.h>
#include <hip/hip_fp16.h>

#define N_NODES 50000
#define N_EDGES 800000
#define DD 96
#define NLAYER 4
#define N_GRAPHS 256
#define BN_EPS 1e-5f
#define GSLABS 4
#define SCH 24       // channels per slab
#define GS_STRIDE 16 // uints per slab row (64 B, one cache line)

// ---------------- workspace layout (units: 4-byte elements) ----------------
enum : size_t {
  O_CNT    = 0,                        // int[N_NODES]
  O_STATS  = O_CNT + N_NODES,          // float[4*192]
  O_POOL   = O_STATS + 4 * 192,        // float[N_GRAPHS*96]
  O_GCNT   = O_POOL + N_GRAPHS * DD,   // int[N_GRAPHS]
  ZERO_END = O_GCNT + N_GRAPHS,
  O_ROWPTR = ZERO_END,                 // int[N_NODES+1]
  O_DIS    = O_ROWPTR + N_NODES + 1,   // float[N_NODES]
  O_BSUMS  = O_DIS + N_NODES,          // int[256]
  O_EDGE   = (O_BSUMS + 256 + 3) & ~size_t(3),  // uint[N_EDGES+8], 16B aligned
  O_HWH    = (O_EDGE + N_EDGES + 8 + 3) & ~size_t(3), // uint[4][50000][16] = 12.8MB
  O_P      = O_HWH + (size_t)GSLABS * N_NODES * GS_STRIDE, // float[N*96] agg
  WS_ELEMS = O_P + (size_t)N_NODES * DD  // ~35.9 MB
};

typedef unsigned int u32x4 __attribute__((ext_vector_type(4)));
typedef float f32x2 __attribute__((ext_vector_type(2)));
typedef _Float16 h2v __attribute__((ext_vector_type(2)));

__device__ __forceinline__ void atomAddF(float* p, float v) {
  unsafeAtomicAdd(p, v);  // native global fp32 atomic
}

__device__ __forceinline__ float2 h2f(unsigned int u) {
  __half2 h = *(__half2*)&u;
  return __half22float2(h);
}

#if defined(__has_builtin)
#if __has_builtin(__builtin_amdgcn_fdot2)
#define HAS_FDOT2 1
#endif
#endif

__device__ __forceinline__ float dot2acc(unsigned int ha, unsigned int wb, float c) {
#ifdef HAS_FDOT2
  union { unsigned int u; h2v h; } a, b;
  a.u = ha; b.u = wb;
  return __builtin_amdgcn_fdot2(a.h, b.h, c, false);
#else
  float2 fa = h2f(ha), fb = h2f(wb);
  return fmaf(fa.x, fb.x, fmaf(fa.y, fb.y, c));
#endif
}

// ---------------- CSR build ----------------
__global__ void k_count(const int* __restrict__ dst, int* __restrict__ cnt) {
  int e = blockIdx.x * blockDim.x + threadIdx.x;
  if (e < N_EDGES) atomicAdd(&cnt[dst[e]], 1);
}

__global__ void k_dis(const int* __restrict__ cnt, float* __restrict__ dis) {
  int n = blockIdx.x * blockDim.x + threadIdx.x;
  if (n < N_NODES) dis[n] = rsqrtf((float)(cnt[n] + 1));  // +1 self loop
}

__global__ void k_partials(const int* __restrict__ cnt, int* __restrict__ bsums) {
  __shared__ int s[256];
  int i = blockIdx.x * 256 + threadIdx.x;
  s[threadIdx.x] = (i < N_NODES) ? cnt[i] : 0;
  __syncthreads();
  for (int off = 128; off > 0; off >>= 1) {
    if (threadIdx.x < off) s[threadIdx.x] += s[threadIdx.x + off];
    __syncthreads();
  }
  if (threadIdx.x == 0) bsums[blockIdx.x] = s[0];
}

__global__ void k_scan_bsums(int* __restrict__ bsums, int nb, int* __restrict__ rowptr) {
  if (threadIdx.x == 0 && blockIdx.x == 0) {
    int run = 0;
    for (int b = 0; b < nb; ++b) { int t = bsums[b]; bsums[b] = run; run += t; }
    rowptr[N_NODES] = run;
  }
}

__global__ void k_scan_write(const int* __restrict__ cnt, const int* __restrict__ bsums,
                             int* __restrict__ rowptr) {
  __shared__ int s[256];
  int i = blockIdx.x * 256 + threadIdx.x;
  int v = (i < N_NODES) ? cnt[i] : 0;
  s[threadIdx.x] = v;
  __syncthreads();
  for (int off = 1; off < 256; off <<= 1) {
    int x = 0;
    if (threadIdx.x >= off) x = s[threadIdx.x - off];
    __syncthreads();
    s[threadIdx.x] += x;
    __syncthreads();
  }
  if (i < N_NODES) rowptr[i] = bsums[blockIdx.x] + s[threadIdx.x] - v;  // exclusive
}

__global__ void k_fill(const int* __restrict__ ei, const int* __restrict__ rowptr,
                       int* __restrict__ cursor, const float* __restrict__ dis,
                       unsigned int* __restrict__ edg) {
  int e = blockIdx.x * blockDim.x + threadIdx.x;
  if (blockIdx.x == 0 && threadIdx.x < 8) edg[N_EDGES + threadIdx.x] = 0;  // pad
  if (e >= N_EDGES) return;
  int s = ei[e];            // src (< 65536)
  int d = ei[N_EDGES + e];  // dst
  int pos = rowptr[d] + atomicAdd(&cursor[d], 1);
  unsigned short wb = __half_as_ushort(__float2half_rn(dis[s] * dis[d]));
  edg[pos] = (unsigned int)s | ((unsigned int)wb << 16);
}

// ---------------- GEMM: hwh(fp16, slab-major) = act(X) @ W via v_dot2_f32_f16 ----
// 192 thr = 24 col-quads x 8 row-groups; 48 rows/block; fp16 W & act tiles in LDS.
__global__ __launch_bounds__(192) void k_gemm(const float* __restrict__ X,
                                              const float* __restrict__ Wg,
                                              const float* __restrict__ stats,
                                              const float* __restrict__ gamma,
                                              const float* __restrict__ beta,
                                              unsigned int* __restrict__ Yu) {
  __shared__ unsigned int Wh2[48 * 96];   // [k2][f] : half2(W[2k2][f], W[2k2+1][f])
  __shared__ unsigned int Hs2[48 * 52];   // [r][k2] : half2(act[r][2k2], act[r][2k2+1])
  __shared__ float sA[96], sC[96];
  const int tid = threadIdx.x;
  const int fg = tid % 24;
  const int rg = tid / 24;
  const int row0 = blockIdx.x * 48;

  if (tid < 96) {
    if (stats) {
      float mu = stats[tid] * (1.f / N_NODES);
      float var = fmaxf(stats[96 + tid] * (1.f / N_NODES) - mu * mu, 0.f);
      float a = gamma[tid] * rsqrtf(var + BN_EPS);
      sA[tid] = a;
      sC[tid] = beta[tid] - mu * a;
    } else {
      sA[tid] = 1.f;
      sC[tid] = 0.f;
    }
  }
  // stage W (does not need sA)
  for (int i = tid; i < 48 * 96; i += 192) {
    int k2 = i / 96, f = i - k2 * 96;
    __half2 p = __floats2half2_rn(Wg[(2 * k2) * 96 + f], Wg[(2 * k2 + 1) * 96 + f]);
    Wh2[i] = *(unsigned int*)&p;
  }
  __syncthreads();  // sA/sC visible
  const bool bn = (stats != nullptr);
  for (int i = tid; i < 48 * 48; i += 192) {
    int r = i / 48, k2 = i - r * 48;
    int gr = row0 + r;
    float v0 = 0.f, v1 = 0.f;
    if (gr < N_NODES) {
      float2 xv = *(const float2*)&X[(size_t)gr * 96 + 2 * k2];
      v0 = xv.x; v1 = xv.y;
      if (bn) {
        v0 = fmaxf(v0 * sA[2 * k2] + sC[2 * k2], 0.f);
        v1 = fmaxf(v1 * sA[2 * k2 + 1] + sC[2 * k2 + 1], 0.f);
      }
    }
    __half2 p = __floats2half2_rn(v0, v1);
    Hs2[r * 52 + k2] = *(unsigned int*)&p;
  }
  __syncthreads();

  float4 acc[6];
#pragma unroll
  for (int j = 0; j < 6; ++j) acc[j] = make_float4(0.f, 0.f, 0.f, 0.f);
  const int f4 = fg * 4;
  for (int k8 = 0; k8 < 48; k8 += 4) {
    uint4 w0 = *(const uint4*)&Wh2[(k8 + 0) * 96 + f4];
    uint4 w1 = *(const uint4*)&Wh2[(k8 + 1) * 96 + f4];
    uint4 w2 = *(const uint4*)&Wh2[(k8 + 2) * 96 + f4];
    uint4 w3 = *(const uint4*)&Wh2[(k8 + 3) * 96 + f4];
#pragma unroll
    for (int j = 0; j < 6; ++j) {
      uint4 h = *(const uint4*)&Hs2[(rg + j * 8) * 52 + k8];
      acc[j].x = dot2acc(h.w, w3.x, dot2acc(h.z, w2.x, dot2acc(h.y, w1.x, dot2acc(h.x, w0.x, acc[j].x))));
      acc[j].y = dot2acc(h.w, w3.y, dot2acc(h.z, w2.y, dot2acc(h.y, w1.y, dot2acc(h.x, w0.y, acc[j].y))));
      acc[j].z = dot2acc(h.w, w3.z, dot2acc(h.z, w2.z, dot2acc(h.y, w1.z, dot2acc(h.x, w0.z, acc[j].z))));
      acc[j].w = dot2acc(h.w, w3.w, dot2acc(h.z, w2.w, dot2acc(h.y, w1.w, dot2acc(h.x, w0.w, acc[j].w))));
    }
  }

  // store fp16, slab-major padded rows: slab = fg/6, uint offset (fg%6)*2 in 16-uint row
  const int slab = fg / 6;
  const int uoff = (fg % 6) * 2;
#pragma unroll
  for (int j = 0; j < 6; ++j) {
    int r = row0 + rg + j * 8;
    if (r < N_NODES) {
      union { uint2 u; __half2 h[2]; } pk;
      pk.h[0] = __floats2half2_rn(acc[j].x, acc[j].y);
      pk.h[1] = __floats2half2_rn(acc[j].z, acc[j].w);
      *(uint2*)&Yu[((size_t)slab * N_NODES + r) * GS_STRIDE + uoff] = pk.u;
    }
  }
}

// ---------------- fused aggregation + BN-stats ----------------
// slab = blockIdx%4 -> XCD pair {s, s+4}; slab rows are 64B (one line), L2-resident.
// Group = 12 lanes per dst node (lane owns 1 uint = 2 ch); wave = 5 nodes.
// Edges: nontemporal uint4 loads (8 edges / 2 instrs), branchless masked tail.
__global__ __launch_bounds__(256) void k_gather(const unsigned int* __restrict__ hw4,
                                                const int* __restrict__ rowptr,
                                                const unsigned int* __restrict__ edg,
                                                const float* __restrict__ dis,
                                                float* __restrict__ agg,
                                                float* __restrict__ stats) {
  __shared__ float sred[48];
  const int tid = threadIdx.x;
  const int slab = blockIdx.x & (GSLABS - 1);
  const int chunk = blockIdx.x >> 2;
  const int wave = tid >> 6;
  const int lane = tid & 63;
  const int g = lane / 12;       // 0..5 (g==5 idle)
  const int ch = lane - g * 12;  // 0..11
  const int n = chunk * 20 + wave * 5 + g;
  const bool valid = (g < 5) && (n < N_NODES);
  const int nc = valid ? n : 0;
  const unsigned int* S = hw4 + (size_t)slab * N_NODES * GS_STRIDE;

  if (tid < 48) sred[tid] = 0.f;

  const int js = valid ? rowptr[nc] : 0;
  const int je = valid ? rowptr[nc + 1] : 0;

  float a0 = 0.f, a1 = 0.f;
  if (valid) {
    float dn = dis[nc];
    float s2 = dn * dn;  // self-loop weight
    float2 f = h2f(S[(size_t)nc * GS_STRIDE + ch]);
    a0 = f.x * s2;
    a1 = f.y * s2;
  }

  const u32x4* e4 = (const u32x4*)edg;
  for (int j = (js & ~3); j < je; j += 8) {
    u32x4 e0 = __builtin_nontemporal_load(&e4[j >> 2]);
    u32x4 e1 = __builtin_nontemporal_load(&e4[(j >> 2) + 1]);
    unsigned int ew[8], rv[8];
#pragma unroll
    for (int k = 0; k < 8; ++k) ew[k] = (k < 4) ? e0[k] : e1[k - 4];
#pragma unroll
    for (int k = 0; k < 8; ++k)
      rv[k] = S[(size_t)(ew[k] & 0xFFFFu) * GS_STRIDE + ch];
#pragma unroll
    for (int k = 0; k < 8; ++k) {
      int jk = j + k;
      float w = (jk >= js && jk < je)
                    ? __half2float(__ushort_as_half((unsigned short)(ew[k] >> 16)))
                    : 0.f;
      float2 f = h2f(rv[k]);
      a0 = fmaf(w, f.x, a0);
      a1 = fmaf(w, f.y, a1);
    }
  }

  if (valid) {
    f32x2 o; o.x = a0; o.y = a1;
    __builtin_nontemporal_store(o, (f32x2*)&agg[(size_t)n * DD + slab * SCH + ch * 2]);
  }

  __syncthreads();
  if (valid) {
    atomicAdd(&sred[ch * 2], a0);          // LDS ds_add_f32
    atomicAdd(&sred[ch * 2 + 1], a1);
    atomicAdd(&sred[24 + ch * 2], a0 * a0);
    atomicAdd(&sred[25 + ch * 2], a1 * a1);
  }
  __syncthreads();
  if (tid < 48) {
    int c = (tid < 24) ? (slab * SCH + tid) : (96 + slab * SCH + (tid - 24));
    atomAddF(&stats[c], sred[tid]);
  }
}

// ---------------- pooling: final BN+ReLU + segment-sum over sorted batch ----------------
__global__ __launch_bounds__(192) void k_pool(const float* __restrict__ h,
                                              const float* __restrict__ stats,
                                              const float* __restrict__ gamma,
                                              const float* __restrict__ beta,
                                              const int* __restrict__ batch,
                                              float* __restrict__ pool) {
  __shared__ float sA[96], sC[96];
  const int tid = threadIdx.x;
  if (tid < 96) {
    float mu = stats[tid] * (1.f / N_NODES);
    float var = fmaxf(stats[96 + tid] * (1.f / N_NODES) - mu * mu, 0.f);
    float a = gamma[tid] * rsqrtf(var + BN_EPS);
    sA[tid] = a;
    sC[tid] = beta[tid] - mu * a;
  }
  __syncthreads();
  const int chain = blockIdx.x * 8 + tid / 24;
  const int q4 = (tid % 24) * 4;
  int n0 = chain * 32;
  if (n0 >= N_NODES) return;
  int n1 = min(n0 + 32, N_NODES);
  float A0 = sA[q4], A1 = sA[q4 + 1], A2 = sA[q4 + 2], A3 = sA[q4 + 3];
  float C0 = sC[q4], C1 = sC[q4 + 1], C2 = sC[q4 + 2], C3 = sC[q4 + 3];
  int cur = batch[n0];
  float4 acc = make_float4(0.f, 0.f, 0.f, 0.f);
  for (int n = n0; n < n1; ++n) {
    int g = batch[n];
    if (g != cur) {
      float* p = &pool[cur * 96 + q4];
      atomAddF(p, acc.x); atomAddF(p + 1, acc.y);
      atomAddF(p + 2, acc.z); atomAddF(p + 3, acc.w);
      acc = make_float4(0.f, 0.f, 0.f, 0.f);
      cur = g;
    }
    const float4 v = *(const float4*)&h[(size_t)n * 96 + q4];
    acc.x += fmaxf(v.x * A0 + C0, 0.f);
    acc.y += fmaxf(v.y * A1 + C1, 0.f);
    acc.z += fmaxf(v.z * A2 + C2, 0.f);
    acc.w += fmaxf(v.w * A3 + C3, 0.f);
  }
  float* p = &pool[cur * 96 + q4];
  atomAddF(p, acc.x); atomAddF(p + 1, acc.y);
  atomAddF(p + 2, acc.z); atomAddF(p + 3, acc.w);
}

__global__ void k_gcount(const int* __restrict__ batch, int* __restrict__ gcnt) {
  int n = blockIdx.x * blockDim.x + threadIdx.x;
  if (n < N_NODES) atomicAdd(&gcnt[batch[n]], 1);
}

__global__ void k_out(const float* __restrict__ pool, const int* __restrict__ gcnt,
                      float* __restrict__ out) {
  int t = blockIdx.x * blockDim.x + threadIdx.x;
  if (t >= N_GRAPHS * 96) return;
  int g = t / 96;
  int c = gcnt[g];
  if (c < 1) c = 1;
  out[t] = pool[t] / (float)c;
}

extern "C" void kernel_launch(void* const* d_in, const int* in_sizes, int n_in,
                              void* d_out, int out_size, void* d_ws, size_t ws_size,
                              hipStream_t stream) {
  const float* x     = (const float*)d_in[0];
  const int*   ei    = (const int*)d_in[1];   // [2, E]: src row then dst row
  const int*   batch = (const int*)d_in[2];
  const float* W     = (const float*)d_in[3]; // [4,96,96]
  // d_in[4] = b : cancels exactly through BatchNorm, unused
  const float* gamma = (const float*)d_in[5]; // [4,96]
  const float* beta  = (const float*)d_in[6];
  float* out = (float*)d_out;

  float* ws = (float*)d_ws;
  int*   cnt    = (int*)(ws + O_CNT);
  float* stats  = ws + O_STATS;
  float* pool   = ws + O_POOL;
  int*   gcnt   = (int*)(ws + O_GCNT);
  int*   rowptr = (int*)(ws + O_ROWPTR);
  float* dis    = ws + O_DIS;
  int*   bsums  = (int*)(ws + O_BSUMS);
  unsigned int* edg = (unsigned int*)(ws + O_EDGE);
  unsigned int* hw4 = (unsigned int*)(ws + O_HWH);
  float* P      = ws + O_P;  // agg (fp32)

  hipMemsetAsync(d_ws, 0, ZERO_END * sizeof(float), stream);

  const int eb = (N_EDGES + 255) / 256;
  const int nb = (N_NODES + 255) / 256;  // 196
  k_count<<<eb, 256, 0, stream>>>(ei + N_EDGES, cnt);
  k_dis<<<nb, 256, 0, stream>>>(cnt, dis);
  k_partials<<<nb, 256, 0, stream>>>(cnt, bsums);
  k_scan_bsums<<<1, 64, 0, stream>>>(bsums, nb, rowptr);
  k_scan_write<<<nb, 256, 0, stream>>>(cnt, bsums, rowptr);
  hipMemsetAsync(cnt, 0, N_NODES * sizeof(int), stream);  // reuse as fill cursors
  k_fill<<<eb, 256, 0, stream>>>(ei, rowptr, cnt, dis, edg);

  const int gemmb = (N_NODES + 47) / 48;                  // 1042
  const int gatherb = GSLABS * ((N_NODES + 19) / 20);     // 4 * 2500 = 10000

  const float* hin = x;
  for (int l = 0; l < NLAYER; ++l) {
    const float* st = (l == 0) ? nullptr : (stats + (l - 1) * 192);
    const float* ga = (l == 0) ? nullptr : (gamma + (l - 1) * 96);
    const float* be = (l == 0) ? nullptr : (beta + (l - 1) * 96);
    k_gemm<<<gemmb, 192, 0, stream>>>(hin, W + l * 96 * 96, st, ga, be, hw4);
    k_gather<<<gatherb, 256, 0, stream>>>(hw4, rowptr, edg, dis, P, stats + l * 192);
    hin = P;
  }

  const int poolb = ((N_NODES + 31) / 32 + 7) / 8;  // 196
  k_pool<<<poolb, 192, 0, stream>>>(P, stats + 3 * 192, gamma + 3 * 96, beta + 3 * 96,
                                    batch, pool);
  k_gcount<<<nb, 256, 0, stream>>>(batch, gcnt);
  k_out<<<(N_GRAPHS * 96 + 255) / 256, 256, 0, stream>>>(pool, gcnt, out);
}

// Round 7
// 830.589 us; speedup vs baseline: 1.1914x; 1.1914x over previous
//
#include <hip/hip_runtime.h>
#include <hip/hip_bf16.h>
#include <hip/hip_fp16.h>

#define N_NODES 50000
#define N_EDGES 800000
#define DD 96
#define NLAYER 4
#define N_GRAPHS 256
#define BN_EPS 1e-5f
#define GSLABS 4
#define SCH 24       // channels per slab
#define GS_STRIDE 16 // uints per slab row (64 B, one cache line)

// ---------------- workspace layout (units: 4-byte elements) ----------------
enum : size_t {
  O_CNT    = 0,                        // int[N_NODES]
  O_STATS  = O_CNT + N_NODES,          // float[4*192]
  O_POOL   = O_STATS + 4 * 192,        // float[N_GRAPHS*96]
  O_GCNT   = O_POOL + N_GRAPHS * DD,   // int[N_GRAPHS]
  ZERO_END = O_GCNT + N_GRAPHS,
  O_ROWPTR = ZERO_END,                 // int[N_NODES+1]
  O_DIS    = O_ROWPTR + N_NODES + 1,   // float[N_NODES]
  O_BSUMS  = O_DIS + N_NODES,          // int[256]
  O_EDGE   = (O_BSUMS + 256 + 3) & ~size_t(3),  // uint[N_EDGES+8], 16B aligned
  O_HWH    = (O_EDGE + N_EDGES + 8 + 3) & ~size_t(3), // uint[4][50000][16] = 12.8MB
  O_P      = O_HWH + (size_t)GSLABS * N_NODES * GS_STRIDE, // float[N*96] agg
  WS_ELEMS = O_P + (size_t)N_NODES * DD  // ~35.9 MB
};

__device__ __forceinline__ void atomAddF(float* p, float v) {
  unsafeAtomicAdd(p, v);  // native global fp32 atomic
}

__device__ __forceinline__ float2 h2f(unsigned int u) {
  __half2 h = *(__half2*)&u;
  return __half22float2(h);
}

// ---------------- CSR build ----------------
__global__ void k_count(const int* __restrict__ dst, int* __restrict__ cnt) {
  int e = blockIdx.x * blockDim.x + threadIdx.x;
  if (e < N_EDGES) atomicAdd(&cnt[dst[e]], 1);
}

__global__ void k_dis(const int* __restrict__ cnt, float* __restrict__ dis) {
  int n = blockIdx.x * blockDim.x + threadIdx.x;
  if (n < N_NODES) dis[n] = rsqrtf((float)(cnt[n] + 1));  // +1 self loop
}

__global__ void k_partials(const int* __restrict__ cnt, int* __restrict__ bsums) {
  __shared__ int s[256];
  int i = blockIdx.x * 256 + threadIdx.x;
  s[threadIdx.x] = (i < N_NODES) ? cnt[i] : 0;
  __syncthreads();
  for (int off = 128; off > 0; off >>= 1) {
    if (threadIdx.x < off) s[threadIdx.x] += s[threadIdx.x + off];
    __syncthreads();
  }
  if (threadIdx.x == 0) bsums[blockIdx.x] = s[0];
}

__global__ void k_scan_bsums(int* __restrict__ bsums, int nb, int* __restrict__ rowptr) {
  if (threadIdx.x == 0 && blockIdx.x == 0) {
    int run = 0;
    for (int b = 0; b < nb; ++b) { int t = bsums[b]; bsums[b] = run; run += t; }
    rowptr[N_NODES] = run;
  }
}

__global__ void k_scan_write(const int* __restrict__ cnt, const int* __restrict__ bsums,
                             int* __restrict__ rowptr) {
  __shared__ int s[256];
  int i = blockIdx.x * 256 + threadIdx.x;
  int v = (i < N_NODES) ? cnt[i] : 0;
  s[threadIdx.x] = v;
  __syncthreads();
  for (int off = 1; off < 256; off <<= 1) {
    int x = 0;
    if (threadIdx.x >= off) x = s[threadIdx.x - off];
    __syncthreads();
    s[threadIdx.x] += x;
    __syncthreads();
  }
  if (i < N_NODES) rowptr[i] = bsums[blockIdx.x] + s[threadIdx.x] - v;  // exclusive
}

__global__ void k_fill(const int* __restrict__ ei, const int* __restrict__ rowptr,
                       int* __restrict__ cursor, const float* __restrict__ dis,
                       unsigned int* __restrict__ edg) {
  int e = blockIdx.x * blockDim.x + threadIdx.x;
  if (blockIdx.x == 0 && threadIdx.x < 8) edg[N_EDGES + threadIdx.x] = 0;  // pad
  if (e >= N_EDGES) return;
  int s = ei[e];            // src (< 65536)
  int d = ei[N_EDGES + e];  // dst
  int pos = rowptr[d] + atomicAdd(&cursor[d], 1);
  unsigned short wb = __half_as_ushort(__float2half_rn(dis[s] * dis[d]));
  edg[pos] = (unsigned int)s | ((unsigned int)wb << 16);
}

// ---------------- GEMM: Y(fp16 slab-major, 64B rows) = act(X) @ W ----------------
// fp32 compute, proven structure: 192 thr = 24 col-quads x 8 row-groups; 48 rows/block.
__global__ __launch_bounds__(192) void k_gemm(const float* __restrict__ X,
                                              const float* __restrict__ Wg,
                                              const float* __restrict__ stats,
                                              const float* __restrict__ gamma,
                                              const float* __restrict__ beta,
                                              unsigned int* __restrict__ Yu) {
  __shared__ float Ws[96 * 96];
  __shared__ float Hs[48][100];
  __shared__ float sA[96], sC[96];
  const int tid = threadIdx.x;
  const int fg = tid % 24;
  const int rg = tid / 24;
  const int row0 = blockIdx.x * 48;

  for (int i = tid; i < 96 * 24; i += 192)
    *(float4*)&Ws[i * 4] = *(const float4*)&Wg[i * 4];
  if (tid < 96) {
    if (stats) {
      float mu = stats[tid] * (1.f / N_NODES);
      float var = fmaxf(stats[96 + tid] * (1.f / N_NODES) - mu * mu, 0.f);
      float a = gamma[tid] * rsqrtf(var + BN_EPS);
      sA[tid] = a;
      sC[tid] = beta[tid] - mu * a;
    } else {
      sA[tid] = 1.f;
      sC[tid] = 0.f;
    }
  }
  __syncthreads();
  const bool bn = (stats != nullptr);
  for (int i = tid; i < 48 * 24; i += 192) {
    int r = i / 24, c4 = (i % 24) * 4;
    int gr = row0 + r;
    float4 v = (gr < N_NODES) ? *(const float4*)&X[(size_t)gr * 96 + c4]
                              : make_float4(0.f, 0.f, 0.f, 0.f);
    if (bn) {
      v.x = fmaxf(v.x * sA[c4] + sC[c4], 0.f);
      v.y = fmaxf(v.y * sA[c4 + 1] + sC[c4 + 1], 0.f);
      v.z = fmaxf(v.z * sA[c4 + 2] + sC[c4 + 2], 0.f);
      v.w = fmaxf(v.w * sA[c4 + 3] + sC[c4 + 3], 0.f);
    }
    *(float4*)&Hs[r][c4] = v;
  }
  __syncthreads();

  float4 acc[6];
#pragma unroll
  for (int j = 0; j < 6; ++j) acc[j] = make_float4(0.f, 0.f, 0.f, 0.f);
  const int f4 = fg * 4;
  for (int k4 = 0; k4 < 96; k4 += 4) {
    float4 w0 = *(const float4*)&Ws[(k4 + 0) * 96 + f4];
    float4 w1 = *(const float4*)&Ws[(k4 + 1) * 96 + f4];
    float4 w2 = *(const float4*)&Ws[(k4 + 2) * 96 + f4];
    float4 w3 = *(const float4*)&Ws[(k4 + 3) * 96 + f4];
#pragma unroll
    for (int j = 0; j < 6; ++j) {
      const float4 h = *(const float4*)&Hs[rg + j * 8][k4];
      acc[j].x += h.x * w0.x + h.y * w1.x + h.z * w2.x + h.w * w3.x;
      acc[j].y += h.x * w0.y + h.y * w1.y + h.z * w2.y + h.w * w3.y;
      acc[j].z += h.x * w0.z + h.y * w1.z + h.z * w2.z + h.w * w3.z;
      acc[j].w += h.x * w0.w + h.y * w1.w + h.z * w2.w + h.w * w3.w;
    }
  }

  // store fp16 into slab-major padded rows: slab = fg/6, uint offset (fg%6)*2
  const int slab = fg / 6;
  const int uoff = (fg % 6) * 2;
#pragma unroll
  for (int j = 0; j < 6; ++j) {
    int r = row0 + rg + j * 8;
    if (r < N_NODES) {
      union { uint2 u; __half2 h[2]; } pk;
      pk.h[0] = __floats2half2_rn(acc[j].x, acc[j].y);
      pk.h[1] = __floats2half2_rn(acc[j].z, acc[j].w);
      *(uint2*)&Yu[((size_t)slab * N_NODES + r) * GS_STRIDE + uoff] = pk.u;
    }
  }
}

// ---------------- fused aggregation + BN-stats ----------------
// slab = blockIdx%4 -> XCD pair; slab rows are 64B (one line), L2-resident (3.2MB).
// Group = 12 lanes per dst node (lane owns 1 uint = 2 ch); wave = 5 nodes.
// Edges: CACHED uint4 loads (8 edges / 2 instrs, L1-served reuse), plain stores.
__global__ __launch_bounds__(256) void k_gather(const unsigned int* __restrict__ hw4,
                                                const int* __restrict__ rowptr,
                                                const unsigned int* __restrict__ edg,
                                                const float* __restrict__ dis,
                                                float* __restrict__ agg,
                                                float* __restrict__ stats) {
  __shared__ float sred[48];
  const int tid = threadIdx.x;
  const int slab = blockIdx.x & (GSLABS - 1);
  const int chunk = blockIdx.x >> 2;
  const int wave = tid >> 6;
  const int lane = tid & 63;
  const int g = lane / 12;       // 0..5 (g==5 idle)
  const int ch = lane - g * 12;  // 0..11
  const int n = chunk * 20 + wave * 5 + g;
  const bool valid = (g < 5) && (n < N_NODES);
  const int nc = valid ? n : 0;
  const unsigned int* S = hw4 + (size_t)slab * N_NODES * GS_STRIDE;

  if (tid < 48) sred[tid] = 0.f;

  const int js = valid ? rowptr[nc] : 0;
  const int je = valid ? rowptr[nc + 1] : 0;

  float a0 = 0.f, a1 = 0.f;
  if (valid) {
    float dn = dis[nc];
    float s2 = dn * dn;  // self-loop weight
    float2 f = h2f(S[(size_t)nc * GS_STRIDE + ch]);
    a0 = f.x * s2;
    a1 = f.y * s2;
  }

  const uint4* e4 = (const uint4*)edg;
  for (int j = (js & ~3); j < je; j += 8) {
    uint4 e0 = e4[j >> 2];
    uint4 e1 = e4[(j >> 2) + 1];
    unsigned int ew[8], rv[8];
    ew[0] = e0.x; ew[1] = e0.y; ew[2] = e0.z; ew[3] = e0.w;
    ew[4] = e1.x; ew[5] = e1.y; ew[6] = e1.z; ew[7] = e1.w;
#pragma unroll
    for (int k = 0; k < 8; ++k)
      rv[k] = S[(size_t)(ew[k] & 0xFFFFu) * GS_STRIDE + ch];
#pragma unroll
    for (int k = 0; k < 8; ++k) {
      int jk = j + k;
      float w = (jk >= js && jk < je)
                    ? __half2float(__ushort_as_half((unsigned short)(ew[k] >> 16)))
                    : 0.f;
      float2 f = h2f(rv[k]);
      a0 = fmaf(w, f.x, a0);
      a1 = fmaf(w, f.y, a1);
    }
  }

  if (valid) {
    *(float2*)&agg[(size_t)n * DD + slab * SCH + ch * 2] = make_float2(a0, a1);
  }

  __syncthreads();
  if (valid) {
    atomicAdd(&sred[ch * 2], a0);          // LDS ds_add_f32
    atomicAdd(&sred[ch * 2 + 1], a1);
    atomicAdd(&sred[24 + ch * 2], a0 * a0);
    atomicAdd(&sred[25 + ch * 2], a1 * a1);
  }
  __syncthreads();
  if (tid < 48) {
    int c = (tid < 24) ? (slab * SCH + tid) : (96 + slab * SCH + (tid - 24));
    atomAddF(&stats[c], sred[tid]);
  }
}

// ---------------- pooling: final BN+ReLU + segment-sum over sorted batch ----------------
__global__ __launch_bounds__(192) void k_pool(const float* __restrict__ h,
                                              const float* __restrict__ stats,
                                              const float* __restrict__ gamma,
                                              const float* __restrict__ beta,
                                              const int* __restrict__ batch,
                                              float* __restrict__ pool) {
  __shared__ float sA[96], sC[96];
  const int tid = threadIdx.x;
  if (tid < 96) {
    float mu = stats[tid] * (1.f / N_NODES);
    float var = fmaxf(stats[96 + tid] * (1.f / N_NODES) - mu * mu, 0.f);
    float a = gamma[tid] * rsqrtf(var + BN_EPS);
    sA[tid] = a;
    sC[tid] = beta[tid] - mu * a;
  }
  __syncthreads();
  const int chain = blockIdx.x * 8 + tid / 24;
  const int q4 = (tid % 24) * 4;
  int n0 = chain * 32;
  if (n0 >= N_NODES) return;
  int n1 = min(n0 + 32, N_NODES);
  float A0 = sA[q4], A1 = sA[q4 + 1], A2 = sA[q4 + 2], A3 = sA[q4 + 3];
  float C0 = sC[q4], C1 = sC[q4 + 1], C2 = sC[q4 + 2], C3 = sC[q4 + 3];
  int cur = batch[n0];
  float4 acc = make_float4(0.f, 0.f, 0.f, 0.f);
  for (int n = n0; n < n1; ++n) {
    int g = batch[n];
    if (g != cur) {
      float* p = &pool[cur * 96 + q4];
      atomAddF(p, acc.x); atomAddF(p + 1, acc.y);
      atomAddF(p + 2, acc.z); atomAddF(p + 3, acc.w);
      acc = make_float4(0.f, 0.f, 0.f, 0.f);
      cur = g;
    }
    const float4 v = *(const float4*)&h[(size_t)n * 96 + q4];
    acc.x += fmaxf(v.x * A0 + C0, 0.f);
    acc.y += fmaxf(v.y * A1 + C1, 0.f);
    acc.z += fmaxf(v.z * A2 + C2, 0.f);
    acc.w += fmaxf(v.w * A3 + C3, 0.f);
  }
  float* p = &pool[cur * 96 + q4];
  atomAddF(p, acc.x); atomAddF(p + 1, acc.y);
  atomAddF(p + 2, acc.z); atomAddF(p + 3, acc.w);
}

__global__ void k_gcount(const int* __restrict__ batch, int* __restrict__ gcnt) {
  int n = blockIdx.x * blockDim.x + threadIdx.x;
  if (n < N_NODES) atomicAdd(&gcnt[batch[n]], 1);
}

__global__ void k_out(const float* __restrict__ pool, const int* __restrict__ gcnt,
                      float* __restrict__ out) {
  int t = blockIdx.x * blockDim.x + threadIdx.x;
  if (t >= N_GRAPHS * 96) return;
  int g = t / 96;
  int c = gcnt[g];
  if (c < 1) c = 1;
  out[t] = pool[t] / (float)c;
}

extern "C" void kernel_launch(void* const* d_in, const int* in_sizes, int n_in,
                              void* d_out, int out_size, void* d_ws, size_t ws_size,
                              hipStream_t stream) {
  const float* x     = (const float*)d_in[0];
  const int*   ei    = (const int*)d_in[1];   // [2, E]: src row then dst row
  const int*   batch = (const int*)d_in[2];
  const float* W     = (const float*)d_in[3]; // [4,96,96]
  // d_in[4] = b : cancels exactly through BatchNorm, unused
  const float* gamma = (const float*)d_in[5]; // [4,96]
  const float* beta  = (const float*)d_in[6];
  float* out = (float*)d_out;

  float* ws = (float*)d_ws;
  int*   cnt    = (int*)(ws + O_CNT);
  float* stats  = ws + O_STATS;
  float* pool   = ws + O_POOL;
  int*   gcnt   = (int*)(ws + O_GCNT);
  int*   rowptr = (int*)(ws + O_ROWPTR);
  float* dis    = ws + O_DIS;
  int*   bsums  = (int*)(ws + O_BSUMS);
  unsigned int* edg = (unsigned int*)(ws + O_EDGE);
  unsigned int* hw4 = (unsigned int*)(ws + O_HWH);
  float* P      = ws + O_P;  // agg (fp32)

  hipMemsetAsync(d_ws, 0, ZERO_END * sizeof(float), stream);

  const int eb = (N_EDGES + 255) / 256;
  const int nb = (N_NODES + 255) / 256;  // 196
  k_count<<<eb, 256, 0, stream>>>(ei + N_EDGES, cnt);
  k_dis<<<nb, 256, 0, stream>>>(cnt, dis);
  k_partials<<<nb, 256, 0, stream>>>(cnt, bsums);
  k_scan_bsums<<<1, 64, 0, stream>>>(bsums, nb, rowptr);
  k_scan_write<<<nb, 256, 0, stream>>>(cnt, bsums, rowptr);
  hipMemsetAsync(cnt, 0, N_NODES * sizeof(int), stream);  // reuse as fill cursors
  k_fill<<<eb, 256, 0, stream>>>(ei, rowptr, cnt, dis, edg);

  const int gemmb = (N_NODES + 47) / 48;                  // 1042
  const int gatherb = GSLABS * ((N_NODES + 19) / 20);     // 4 * 2500 = 10000

  const float* hin = x;
  for (int l = 0; l < NLAYER; ++l) {
    const float* st = (l == 0) ? nullptr : (stats + (l - 1) * 192);
    const float* ga = (l == 0) ? nullptr : (gamma + (l - 1) * 96);
    const float* be = (l == 0) ? nullptr : (beta + (l - 1) * 96);
    k_gemm<<<gemmb, 192, 0, stream>>>(hin, W + l * 96 * 96, st, ga, be, hw4);
    k_gather<<<gatherb, 256, 0, stream>>>(hw4, rowptr, edg, dis, P, stats + l * 192);
    hin = P;
  }

  const int poolb = ((N_NODES + 31) / 32 + 7) / 8;  // 196
  k_pool<<<poolb, 192, 0, stream>>>(P, stats + 3 * 192, gamma + 3 * 96, beta + 3 * 96,
                                    batch, pool);
  k_gcount<<<nb, 256, 0, stream>>>(batch, gcnt);
  k_out<<<(N_GRAPHS * 96 + 255) / 256, 256, 0, stream>>>(pool, gcnt, out);
}